// Round 11
// baseline (251.849 us; speedup 1.0000x reference)
//
#include <hip/hip_runtime.h>
#include <cmath>

#define NCC 151
#define NRCH 51
#define BDIM 32
#define NOBJ 100
#define DDIM 4096
#define HDIM 1024
#define TDIM (BDIM * NOBJ)   // 3200
#define MPAD 3328            // TDIM padded to multiple of 256

typedef __bf16 bf16_t;
typedef __bf16 bf16x8 __attribute__((ext_vector_type(8)));
typedef __bf16 bf16x4 __attribute__((ext_vector_type(4)));
typedef float f32x4 __attribute__((ext_vector_type(4)));

// ---------------------------------------------------------------------------
// 128x128 bf16 MFMA GEMM (R8-proven single-buffer): C = act(A @ Bt^T)
// 256 threads = 4 waves (2x2). XOR-swizzled LDS. MODE0 XCD-chunk swizzle.
// Used for G2/G3 (M=3200 exact multiple of 128, bf16 out, relu).
// ---------------------------------------------------------------------------
template <bool RELU>
__global__ __launch_bounds__(256) void gemm128(
    const bf16_t* __restrict__ A, const bf16_t* __restrict__ Bt,
    bf16_t* __restrict__ C, int N, int K) {
  __shared__ __align__(16) bf16_t Asm[128 * 64];
  __shared__ __align__(16) bf16_t Bsm[128 * 64];
  const int tid = threadIdx.x;
  const int lane = tid & 63;
  const int w = tid >> 6;
  const int wm = w >> 1, wn = w & 1;

  const int nx = gridDim.x, ny = gridDim.y;
  const int h = blockIdx.x + nx * blockIdx.y;
  const int nwg = nx * ny;  // % 8 == 0
  const int q = nwg >> 3;
  const int lin = (h & 7) * q + (h >> 3);
  const int by = lin % ny;
  const int bx = lin / ny;

  const int bm = by * 128, bn = bx * 128;
  const int lr = lane & 15, lk = lane >> 4;

  f32x4 acc[4][4];
#pragma unroll
  for (int m = 0; m < 4; ++m)
#pragma unroll
    for (int n = 0; n < 4; ++n) acc[m][n] = (f32x4){0.f, 0.f, 0.f, 0.f};

  const int srow = tid >> 3, sslot = tid & 7;
  char* ldsA = (char*)Asm;
  char* ldsB = (char*)Bsm;

  for (int kt = 0; kt < K; kt += 64) {
    __syncthreads();
#pragma unroll
    for (int i = 0; i < 4; ++i) {
      const int row = i * 32 + srow;
      const int kc = sslot ^ (row & 7);
      const bf16_t* ga = A + (size_t)(bm + row) * K + kt + kc * 8;
      const bf16_t* gb = Bt + (size_t)(bn + row) * K + kt + kc * 8;
      __builtin_amdgcn_global_load_lds(
          (const __attribute__((address_space(1))) void*)ga,
          (__attribute__((address_space(3))) void*)(ldsA + i * 4096 + w * 1024),
          16, 0, 0);
      __builtin_amdgcn_global_load_lds(
          (const __attribute__((address_space(1))) void*)gb,
          (__attribute__((address_space(3))) void*)(ldsB + i * 4096 + w * 1024),
          16, 0, 0);
    }
    __syncthreads();

    bf16x8 af[4][2], bfr[4][2];
#pragma unroll
    for (int m = 0; m < 4; ++m) {
      const int row = wm * 64 + m * 16 + lr;
#pragma unroll
      for (int kk = 0; kk < 2; ++kk) {
        const int slot = kk * 4 + lk;
        af[m][kk] =
            *(const bf16x8*)(ldsA + row * 128 + ((slot ^ (lr & 7)) << 4));
      }
    }
#pragma unroll
    for (int n = 0; n < 4; ++n) {
      const int row = wn * 64 + n * 16 + lr;
#pragma unroll
      for (int kk = 0; kk < 2; ++kk) {
        const int slot = kk * 4 + lk;
        bfr[n][kk] =
            *(const bf16x8*)(ldsB + row * 128 + ((slot ^ (lr & 7)) << 4));
      }
    }
#pragma unroll
    for (int m = 0; m < 4; ++m)
#pragma unroll
      for (int n = 0; n < 4; ++n) {
        acc[m][n] = __builtin_amdgcn_mfma_f32_16x16x32_bf16(
            af[m][0], bfr[n][0], acc[m][n], 0, 0, 0);
        acc[m][n] = __builtin_amdgcn_mfma_f32_16x16x32_bf16(
            af[m][1], bfr[n][1], acc[m][n], 0, 0, 0);
      }
  }

  const int or0 = bm + wm * 64 + lk * 4;
  const int oc0 = bn + wn * 64 + lr;
#pragma unroll
  for (int m = 0; m < 4; ++m)
#pragma unroll
    for (int n = 0; n < 4; ++n)
#pragma unroll
      for (int r = 0; r < 4; ++r) {
        float v = acc[m][n][r];
        if (RELU) v = fmaxf(v, 0.f);
        C[(size_t)(or0 + m * 16 + r) * N + (oc0 + n * 16)] = (bf16_t)v;
      }
}

// ---------------------------------------------------------------------------
// 256x256 bf16 MFMA GEMM (R11): 512 threads = 8 waves (2M x 4N), BK=64,
// single-buffered 64KB LDS. 4x arithmetic intensity of gemm128 — targets the
// staging-throughput-bound regime (1 block/CU). Same swizzle/fragment/epilogue
// mapping as gemm128 (proven). Rows >= M masked at store; A must be padded to
// 256-multiple rows (garbage pad rows are finite, never stored).
// SPLITK>1: bf16 partial to Cout + bz*MN (K/SPLITK must be 64-aligned).
// ADDBF16: out fp32 = relu(gemm) + add(bf16).
// ---------------------------------------------------------------------------
template <bool RELU, bool ADDBF16, int SPLITK>
__global__ __launch_bounds__(512) void gemm256(
    const bf16_t* __restrict__ A,   // [Mpad][K]
    const bf16_t* __restrict__ Bt,  // [N][K]
    const bf16_t* __restrict__ add, // bf16 residual when ADDBF16
    void* __restrict__ Cout,        // bf16 [M][N]; fp32 if ADDBF16
    int M, int N, int K, size_t MN) {
  __shared__ __align__(16) bf16_t Asm[256 * 64];
  __shared__ __align__(16) bf16_t Bsm[256 * 64];
  const int tid = threadIdx.x;
  const int lane = tid & 63;
  const int w = tid >> 6;            // 0..7
  const int wm = w >> 2, wn = w & 3; // 2 x 4 wave grid

  const int nx = gridDim.x, ny = gridDim.y, nz = gridDim.z;
  const int h = blockIdx.x + nx * (blockIdx.y + ny * blockIdx.z);
  const int nwg = nx * ny * nz;  // % 8 == 0
  const int q = nwg >> 3;
  const int lin = (h & 7) * q + (h >> 3);
  const int by = lin % ny;
  const int r2 = lin / ny;
  const int bx = r2 % nx;
  const int bz = r2 / nx;

  const int bm = by * 256, bn = bx * 256;
  const int lr = lane & 15, lk = lane >> 4;

  int kBeg = 0, kEnd = K;
  if (SPLITK > 1) {
    const int chunk = K / SPLITK;  // 64-aligned by construction
    kBeg = bz * chunk;
    kEnd = kBeg + chunk;
  }

  f32x4 acc[8][4];
#pragma unroll
  for (int m = 0; m < 8; ++m)
#pragma unroll
    for (int n = 0; n < 4; ++n) acc[m][n] = (f32x4){0.f, 0.f, 0.f, 0.f};

  const int srow = tid >> 3;   // 0..63 (row within 64-row i-group)
  const int sslot = tid & 7;
  char* ldsA = (char*)Asm;
  char* ldsB = (char*)Bsm;

  for (int kt = kBeg; kt < kEnd; kt += 64) {
    __syncthreads();
#pragma unroll
    for (int i = 0; i < 4; ++i) {
      const int row = i * 64 + srow;
      const int kc = sslot ^ (row & 7);
      const bf16_t* ga = A + (size_t)(bm + row) * K + kt + kc * 8;
      const bf16_t* gb = Bt + (size_t)(bn + row) * K + kt + kc * 8;
      __builtin_amdgcn_global_load_lds(
          (const __attribute__((address_space(1))) void*)ga,
          (__attribute__((address_space(3))) void*)(ldsA + i * 8192 + w * 1024),
          16, 0, 0);
      __builtin_amdgcn_global_load_lds(
          (const __attribute__((address_space(1))) void*)gb,
          (__attribute__((address_space(3))) void*)(ldsB + i * 8192 + w * 1024),
          16, 0, 0);
    }
    __syncthreads();

#pragma unroll
    for (int kk = 0; kk < 2; ++kk) {
      bf16x8 af[8], bfr[4];
      const int slot = kk * 4 + lk;
#pragma unroll
      for (int n = 0; n < 4; ++n) {
        const int row = wn * 64 + n * 16 + lr;
        bfr[n] = *(const bf16x8*)(ldsB + row * 128 + ((slot ^ (lr & 7)) << 4));
      }
#pragma unroll
      for (int m = 0; m < 8; ++m) {
        const int row = wm * 128 + m * 16 + lr;
        af[m] = *(const bf16x8*)(ldsA + row * 128 + ((slot ^ (lr & 7)) << 4));
      }
#pragma unroll
      for (int m = 0; m < 8; ++m)
#pragma unroll
        for (int n = 0; n < 4; ++n)
          acc[m][n] = __builtin_amdgcn_mfma_f32_16x16x32_bf16(
              af[m], bfr[n], acc[m][n], 0, 0, 0);
    }
  }

  const int or0 = bm + wm * 128 + lk * 4;
  const int oc0 = bn + wn * 64 + lr;
#pragma unroll
  for (int m = 0; m < 8; ++m)
#pragma unroll
    for (int n = 0; n < 4; ++n)
#pragma unroll
      for (int r = 0; r < 4; ++r) {
        const int row = or0 + m * 16 + r;
        if (row >= M) continue;  // mask padded rows
        float v = acc[m][n][r];
        const size_t off = (size_t)row * N + (oc0 + n * 16);
        if (SPLITK > 1) {
          ((bf16_t*)Cout)[bz * MN + off] = (bf16_t)v;
        } else {
          if (RELU) v = fmaxf(v, 0.f);
          if (ADDBF16)
            ((float*)Cout)[off] = v + (float)add[off];
          else
            ((bf16_t*)Cout)[off] = (bf16_t)v;
        }
      }
}

// reduce NPART bf16 partials -> relu -> bf16
template <int NPART>
__global__ __launch_bounds__(256) void reduceN_kernel(
    const bf16_t* __restrict__ p, bf16_t* __restrict__ out, int n8,
    size_t MN) {
  int i = blockIdx.x * 256 + threadIdx.x;
  if (i >= n8) return;
  float s[8] = {};
#pragma unroll
  for (int z = 0; z < NPART; ++z) {
    bf16x8 v = *(const bf16x8*)(p + z * MN + (size_t)i * 8);
#pragma unroll
    for (int j = 0; j < 8; ++j) s[j] += (float)v[j];
  }
  bf16x8 o;
#pragma unroll
  for (int j = 0; j < 8; ++j) o[j] = (bf16_t)fmaxf(s[j], 0.f);
  *(bf16x8*)(out + (size_t)i * 8) = o;
}

// ---------------------------------------------------------------------------
__global__ __launch_bounds__(256) void cvt_bf16_kernel(
    const float* __restrict__ in, bf16_t* __restrict__ out, int n4) {
  int i = blockIdx.x * 256 + threadIdx.x;
  if (i >= n4) return;
  float4 v = ((const float4*)in)[i];
  bf16x4 o = {(bf16_t)v.x, (bf16_t)v.y, (bf16_t)v.z, (bf16_t)v.w};
  ((bf16x4*)out)[i] = o;
}

// ---------------------------------------------------------------------------
// W[K][N] fp32 -> Wt[N][K] bf16, 32x32 LDS tile transpose
// ---------------------------------------------------------------------------
__global__ __launch_bounds__(256) void transT_kernel(
    const float* __restrict__ in, bf16_t* __restrict__ out, int K, int N) {
  __shared__ float t[32][33];
  const int n0 = blockIdx.x * 32, k0 = blockIdx.y * 32;
  const int tx = threadIdx.x & 31, ty = threadIdx.x >> 5;  // 32 x 8
#pragma unroll
  for (int i = 0; i < 4; ++i)
    t[ty + i * 8][tx] = in[(size_t)(k0 + ty + i * 8) * N + n0 + tx];
  __syncthreads();
#pragma unroll
  for (int i = 0; i < 4; ++i)
    out[(size_t)(n0 + ty + i * 8) * K + k0 + tx] = (bf16_t)t[tx][ty + i * 8];
}

// ---------------------------------------------------------------------------
// Conv chain (R8/R10 proven structure)
// ---------------------------------------------------------------------------
__global__ __launch_bounds__(256) void prep_w1r_kernel(
    const float* __restrict__ w1, float* __restrict__ w1r) {
  int idx = blockIdx.x * 256 + threadIdx.x;
  if (idx >= NRCH * 90) return;
  int ci = idx / 90, r = idx % 90, k9 = r / 10, co = r % 10;
  w1r[idx] = w1[((co * NRCH + ci) * 3 + k9 / 3) * 3 + (k9 % 3)];
}

__global__ __launch_bounds__(128) void femb1_kernel(
    const float* __restrict__ femb, const float* __restrict__ w1r,
    float* __restrict__ femb1) {
  __shared__ float row[NRCH];
  const int p = blockIdx.x;
  if (threadIdx.x < NRCH)
    row[threadIdx.x] = femb[(size_t)p * NRCH + threadIdx.x];
  __syncthreads();
  const int t = threadIdx.x;
  if (t >= 90) return;
  float acc = 0.f;
#pragma unroll
  for (int ci = 0; ci < NRCH; ++ci) acc += row[ci] * w1r[ci * 90 + t];
  femb1[((size_t)p * 9 + t / 10) * 12 + (t % 10)] = acc;
}

__global__ __launch_bounds__(256) void conv1g_kernel(
    const int* __restrict__ preds, const float* __restrict__ femb1,
    float* __restrict__ x1) {
  int idx = blockIdx.x * 256 + threadIdx.x;
  if (idx >= BDIM * NOBJ * NOBJ) return;
  int j = idx % NOBJ;
  int i = (idx / NOBJ) % NOBJ;
  int b = idx / (NOBJ * NOBJ);
  const int* pr = preds + b * NOBJ;
  int li[3], lj[3];
#pragma unroll
  for (int d = 0; d < 3; ++d) {
    li[d] = pr[min(max(i + d - 1, 0), NOBJ - 1)];
    lj[d] = pr[min(max(j + d - 1, 0), NOBJ - 1)];
  }
  f32x4 a0 = {0.f, 0.f, 0.f, 0.f}, a1 = a0, a2 = a0;
#pragma unroll
  for (int kh = 0; kh < 3; ++kh) {
    int ii = i + kh - 1;
    if (ii < 0 || ii >= NOBJ) continue;
#pragma unroll
    for (int kw = 0; kw < 3; ++kw) {
      int jj = j + kw - 1;
      if (jj < 0 || jj >= NOBJ) continue;
      int p = li[kh] * NCC + lj[kw];
      const f32x4* f =
          (const f32x4*)(femb1 + ((size_t)p * 9 + kh * 3 + kw) * 12);
      a0 += f[0];
      a1 += f[1];
      a2 += f[2];
    }
  }
  f32x4* o = (f32x4*)(x1 + (size_t)idx * 12);
  o[0] = a0;
  o[1] = a1;
  o[2] = a2;
}

__global__ __launch_bounds__(256) void conv23_kernel(
    const float* __restrict__ x1, const float* __restrict__ w2,
    const float* __restrict__ w3, float* __restrict__ adj) {
  __shared__ float w[90];
  if (threadIdx.x < 90) {
    const int k9 = threadIdx.x / 10, c2 = threadIdx.x % 10;
    float a = 0.f;
#pragma unroll
    for (int c3 = 0; c3 < 5; ++c3)
      a += w3[c3] * w2[(c3 * 10 + c2) * 9 + k9];
    w[threadIdx.x] = a;
  }
  __syncthreads();
  int idx = blockIdx.x * 256 + threadIdx.x;
  if (idx >= BDIM * NOBJ * NOBJ) return;
  int j = idx % NOBJ;
  int i = (idx / NOBJ) % NOBJ;
  int b = idx / (NOBJ * NOBJ);
  float acc = 0.f;
  const float* xb = x1 + (size_t)b * NOBJ * NOBJ * 12;
#pragma unroll
  for (int kh = 0; kh < 3; ++kh) {
    int ii = i + kh - 1;
    if (ii < 0 || ii >= NOBJ) continue;
#pragma unroll
    for (int kw = 0; kw < 3; ++kw) {
      int jj = j + kw - 1;
      if (jj < 0 || jj >= NOBJ) continue;
      const float* xr = xb + (ii * NOBJ + jj) * 12;
      const float* wr = w + (kh * 3 + kw) * 10;
#pragma unroll
      for (int c = 0; c < 10; ++c) acc += wr[c] * xr[c];
    }
  }
  adj[idx] = tanhf(acc);
}

// ---------------------------------------------------------------------------
// einsum via MFMA: ofl_u[b] = adj[b] (100x100) @ u1[b] (100x1024)
// ---------------------------------------------------------------------------
__global__ __launch_bounds__(256) void einsum_mfma_kernel(
    const float* __restrict__ adj, const bf16_t* __restrict__ u1,
    bf16_t* __restrict__ ofl) {
  __shared__ __align__(16) bf16_t As[128 * 128];
  __shared__ __align__(16) bf16_t Us[128 * 128];
  const int b = blockIdx.y;
  const int h0 = blockIdx.x * 128;
  const int tid = threadIdx.x, lane = tid & 63, w = tid >> 6;
  const int wm = w >> 1, wn = w & 1;
  const int lr = lane & 15, lk = lane >> 4;

  {
    f32x4 z = {0.f, 0.f, 0.f, 0.f};
#pragma unroll
    for (int i = 0; i < 8; ++i) ((f32x4*)As)[tid + i * 256] = z;
#pragma unroll
    for (int i = 0; i < 8; ++i) ((f32x4*)Us)[tid + i * 256] = z;
  }
  __syncthreads();

  const float* ab = adj + (size_t)b * 10000;
#pragma unroll
  for (int i = 0; i < 10; ++i) {
    int idx = tid + i * 256;
    if (idx < 2500) {
      int row = idx / 25, kc = idx % 25;
      f32x4 v = ((const f32x4*)ab)[idx];
      bf16x4 o = {(bf16_t)v[0], (bf16_t)v[1], (bf16_t)v[2], (bf16_t)v[3]};
      int slot = kc >> 1;
      *(bf16x4*)((char*)As + row * 256 + ((slot ^ (row & 7)) << 4) +
                 (kc & 1) * 8) = o;
    }
  }

  const bf16_t* ub = u1 + (size_t)b * 100 * HDIM + h0;
#pragma unroll
  for (int i = 0; i < 7; ++i) {
    int idx = tid + i * 256;
    if (idx < 1600) {
      int hc = idx / 100, m = idx % 100;
      bf16x8 v = *(const bf16x8*)(ub + (size_t)m * HDIM + hc * 8);
      int slot = m >> 3, mr = m & 7;
#pragma unroll
      for (int j = 0; j < 8; ++j) {
        int h = hc * 8 + j;
        *((bf16_t*)((char*)Us + h * 256 + ((slot ^ (h & 7)) << 4) + mr * 2)) =
            v[j];
      }
    }
  }
  __syncthreads();

  f32x4 acc[4][4];
#pragma unroll
  for (int m = 0; m < 4; ++m)
#pragma unroll
    for (int n = 0; n < 4; ++n) acc[m][n] = (f32x4){0.f, 0.f, 0.f, 0.f};

#pragma unroll
  for (int ks = 0; ks < 4; ++ks) {
    bf16x8 a[4], u[4];
#pragma unroll
    for (int m = 0; m < 4; ++m) {
      int row = wm * 64 + m * 16 + lr;
      int slot = ks * 4 + lk;
      a[m] = *(const bf16x8*)((char*)As + row * 256 + ((slot ^ (lr & 7)) << 4));
    }
#pragma unroll
    for (int n = 0; n < 4; ++n) {
      int row = wn * 64 + n * 16 + lr;
      int slot = ks * 4 + lk;
      u[n] = *(const bf16x8*)((char*)Us + row * 256 + ((slot ^ (lr & 7)) << 4));
    }
#pragma unroll
    for (int m = 0; m < 4; ++m)
#pragma unroll
      for (int n = 0; n < 4; ++n)
        acc[m][n] = __builtin_amdgcn_mfma_f32_16x16x32_bf16(a[m], u[n],
                                                            acc[m][n], 0, 0, 0);
  }

  const int or0 = wm * 64 + lk * 4;
  const int oc0 = h0 + wn * 64 + lr;
#pragma unroll
  for (int m = 0; m < 4; ++m)
#pragma unroll
    for (int n = 0; n < 4; ++n)
#pragma unroll
      for (int r = 0; r < 4; ++r) {
        int row = or0 + m * 16 + r;
        if (row < 100)
          ofl[((size_t)b * 100 + row) * HDIM + oc0 + n * 16] =
              (bf16_t)acc[m][n][r];
      }
}

// ---------------------------------------------------------------------------
extern "C" void kernel_launch(void* const* d_in, const int* in_sizes, int n_in,
                              void* d_out, int out_size, void* d_ws,
                              size_t ws_size, hipStream_t stream) {
  const float* enc = (const float*)d_in[0];
  const float* W_comp = (const float*)d_in[1];
  const float* W_ou1 = (const float*)d_in[2];
  const float* W_ofc = (const float*)d_in[3];
  const float* W_dec = (const float*)d_in[4];
  const float* conv1w = (const float*)d_in[5];
  const float* conv2w = (const float*)d_in[6];
  const float* conv3w = (const float*)d_in[7];
  const float* femb = (const float*)d_in[8];
  const int* preds = (const int*)d_in[9];
  float* out = (float*)d_out;
  char* wsb = (char*)d_ws;

  const size_t MN = (size_t)TDIM * HDIM;  // 3,276,800

  // workspace (bytes), peak ~77.4MB (ws >= 112MB proven in R1).
  // encb/u_m padded to MPAD=3328 rows for 256-tiles (pad rows finite garbage,
  // never stored). Liveness: part4 dead after reduce4; Wou1T dead after G2;
  // comp dead after G2; femb1 dead after conv1g; x1 dead after conv23;
  // phase-C (ofl_u/WofcT/u_m/WdecT) overlays only dead regions.
  bf16_t* encb   = (bf16_t*)(wsb + 0);           // 27,262,976 (MPAD, LIVE->G4)
  bf16_t* WcompT = (bf16_t*)(wsb + 27262976);    //  8,388,608 (ends 35.65M)
  bf16_t* comp   = (bf16_t*)(wsb + 35651584);    //  6,553,600 (ends 42.21M)
  bf16_t* part4  = (bf16_t*)(wsb + 42205184);    // 26,214,400 (ends 68.42M)
  bf16_t* Wou1T  = (bf16_t*)(wsb + 42205184);    //  2,097,152 (after reduce4)
  float*  femb1  = (float*)(wsb + 44302336);     //  9,850,032 (ends 54.15M)
  float*  w1r    = (float*)(wsb + 54152368);     //     18,360 (ends 54.17M)
  float*  x1     = (float*)(wsb + 54170752);     // 15,360,000 (ends 69.53M)
  bf16_t* obj_u1 = (bf16_t*)(wsb + 69530752);    //  6,553,600 (ends 76.08M)
  float*  adj    = (float*)(wsb + 76084352);     //  1,280,000 (ends 77.36M)
  // phase C
  bf16_t* ofl_u  = (bf16_t*)(wsb + 27262976);    //  6,553,600 (over WcompT)
  bf16_t* WofcT  = (bf16_t*)(wsb + 33816576);    //  2,097,152
  bf16_t* u_m    = (bf16_t*)(wsb + 35913728);    //  6,815,744 (MPAD, ->42.73M)
  bf16_t* WdecT  = (bf16_t*)(wsb + 42729472);    //  8,388,608 (ends 51.12M)

  const int n8 = (int)(MN / 8);  // 409,600 -> 1600 blocks for reduceN

  // --- conversions for GEMM1 ---
  cvt_bf16_kernel<<<(TDIM * DDIM / 4 + 255) / 256, 256, 0, stream>>>(
      enc, encb, TDIM * DDIM / 4);
  transT_kernel<<<dim3(HDIM / 32, DDIM / 32), 256, 0, stream>>>(
      W_comp, WcompT, DDIM, HDIM);

  // 1. comp = relu(enc @ W_comp)  M=3200 N=1024 K=4096
  //    256^2 tile, split-K=4 (grid 4x13x4 = 208 blocks), bf16 partials
  gemm256<false, false, 4><<<dim3(HDIM / 256, MPAD / 256, 4), 512, 0,
                             stream>>>(encb, WcompT, nullptr, part4, TDIM,
                                       HDIM, DDIM, MN);
  reduceN_kernel<4><<<n8 / 256, 256, 0, stream>>>(part4, comp, n8, MN);

  // 2. obj_u1 = relu(comp @ W_ou1) M=3200 N=1024 K=1024 (128^2, proven)
  transT_kernel<<<dim3(HDIM / 32, HDIM / 32), 256, 0, stream>>>(
      W_ou1, Wou1T, HDIM, HDIM);
  gemm128<true><<<dim3(HDIM / 128, TDIM / 128), 256, 0, stream>>>(
      comp, Wou1T, obj_u1, HDIM, HDIM);

  // 3. conv chain
  prep_w1r_kernel<<<(NRCH * 90 + 255) / 256, 256, 0, stream>>>(conv1w, w1r);
  femb1_kernel<<<NCC * NCC, 128, 0, stream>>>(femb, w1r, femb1);
  conv1g_kernel<<<(BDIM * NOBJ * NOBJ + 255) / 256, 256, 0, stream>>>(
      preds, femb1, x1);
  conv23_kernel<<<(BDIM * NOBJ * NOBJ + 255) / 256, 256, 0, stream>>>(
      x1, conv2w, conv3w, adj);

  // conversions for GEMM3/4
  transT_kernel<<<dim3(HDIM / 32, HDIM / 32), 256, 0, stream>>>(
      W_ofc, WofcT, HDIM, HDIM);
  transT_kernel<<<dim3(DDIM / 32, HDIM / 32), 256, 0, stream>>>(
      W_dec, WdecT, HDIM, DDIM);

  // 7. einsum via MFMA -> ofl_u (bf16)
  einsum_mfma_kernel<<<dim3(HDIM / 128, BDIM), 256, 0, stream>>>(adj, obj_u1,
                                                                 ofl_u);

  // 8. u_m = relu(ofl_u @ W_ofc)  M=3200 N=1024 K=1024 (128^2, proven)
  gemm128<true><<<dim3(HDIM / 128, TDIM / 128), 256, 0, stream>>>(
      ofl_u, WofcT, u_m, HDIM, HDIM);

  // 9. out = relu(u_m @ W_dec) + enc(bf16)  M=3200 N=4096 K=1024
  //    256^2 tile (grid 16x13 = 208 blocks), fp32 out
  gemm256<true, true, 1><<<dim3(DDIM / 256, MPAD / 256, 1), 512, 0, stream>>>(
      u_m, WdecT, encb, out, TDIM, DDIM, HDIM, MN);
}

// Round 12
// 243.162 us; speedup vs baseline: 1.0357x; 1.0357x over previous
//
#include <hip/hip_runtime.h>
#include <cmath>

#define NCC 151
#define NRCH 51
#define BDIM 32
#define NOBJ 100
#define DDIM 4096
#define HDIM 1024
#define TDIM (BDIM * NOBJ)   // 3200

typedef __bf16 bf16_t;
typedef __bf16 bf16x8 __attribute__((ext_vector_type(8)));
typedef __bf16 bf16x4 __attribute__((ext_vector_type(4)));
typedef float f32x4 __attribute__((ext_vector_type(4)));

// ---------------------------------------------------------------------------
// bf16 MFMA GEMM (R8-proven single-buffer): C = act(A @ Bt^T) (+ add)
// 128x128 tile, BK=64, 256 threads = 4 waves (2x2), 16x16x32 MFMA.
// XOR-swizzled LDS (rule #21).
// MODE 0: bijective XCD-chunk swizzle (nwg % 8 == 0).
// MODE 3 (G1, SPLITK=4, grid 832 flat): XCD-pair owns one K=1024 plane,
//   L2-sized A-chunks, 8 idle pad blocks.
// SPLITK>1: bf16 partial to Cout + bz*MN. ADDBF16: fp32 out = relu + add.
// ---------------------------------------------------------------------------
template <bool RELU, bool ADDBF16, int SPLITK, int MODE>
__global__ __launch_bounds__(256) void gemm_bf16(
    const bf16_t* __restrict__ A,   // [M][K] row-major
    const bf16_t* __restrict__ Bt,  // [N][K] row-major
    const bf16_t* __restrict__ add, // bf16 residual when ADDBF16
    void* __restrict__ Cout,        // bf16 [M][N]; fp32 if ADDBF16
    int N, int K, size_t MN) {
  __shared__ __align__(16) bf16_t Asm[128 * 64];
  __shared__ __align__(16) bf16_t Bsm[128 * 64];
  const int tid = threadIdx.x;
  const int lane = tid & 63;
  const int w = tid >> 6;
  const int wm = w >> 1, wn = w & 1;

  const int nx = gridDim.x, ny = gridDim.y, nz = gridDim.z;
  const int h = blockIdx.x + nx * (blockIdx.y + ny * blockIdx.z);
  int bx, by, bz;
  if (MODE == 3) {
    const int xcd = h & 7, s = h >> 3;   // s in [0,104)
    bz = xcd >> 1;
    const int half = xcd & 1;
    if (half == 1 && s >= 96) return;    // idle pad blocks (block-uniform)
    const int c = s / 40;
    if (c < 2) {
      const int within = s % 40;
      bx = within / 5;
      by = (half ? 13 : 0) + c * 5 + within % 5;
    } else if (half == 0) {
      const int w2 = s - 80;
      bx = w2 / 3;
      by = 10 + w2 % 3;
    } else {
      const int w2 = s - 80;
      bx = w2 / 2;
      by = 23 + w2 % 2;
    }
  } else {
    const int nwg = nx * ny * nz;  // % 8 == 0
    const int q = nwg >> 3;
    const int lin = (h & 7) * q + (h >> 3);
    by = lin % ny;
    const int r = lin / ny;
    bx = r % nx;
    bz = r / nx;
  }

  const int bm = by * 128, bn = bx * 128;
  const int lr = lane & 15, lk = lane >> 4;

  int kBeg = 0, kEnd = K;
  if (SPLITK > 1) {
    const int chunk = (((K / 64) + SPLITK - 1) / SPLITK) * 64;
    kBeg = bz * chunk;
    kEnd = min(K, kBeg + chunk);
  }

  f32x4 acc[4][4];
#pragma unroll
  for (int m = 0; m < 4; ++m)
#pragma unroll
    for (int n = 0; n < 4; ++n) acc[m][n] = (f32x4){0.f, 0.f, 0.f, 0.f};

  const int srow = tid >> 3, sslot = tid & 7;
  char* ldsA = (char*)Asm;
  char* ldsB = (char*)Bsm;

  for (int kt = kBeg; kt < kEnd; kt += 64) {
    __syncthreads();
#pragma unroll
    for (int i = 0; i < 4; ++i) {
      const int row = i * 32 + srow;
      const int kc = sslot ^ (row & 7);
      const bf16_t* ga = A + (size_t)(bm + row) * K + kt + kc * 8;
      const bf16_t* gb = Bt + (size_t)(bn + row) * K + kt + kc * 8;
      __builtin_amdgcn_global_load_lds(
          (const __attribute__((address_space(1))) void*)ga,
          (__attribute__((address_space(3))) void*)(ldsA + i * 4096 + w * 1024),
          16, 0, 0);
      __builtin_amdgcn_global_load_lds(
          (const __attribute__((address_space(1))) void*)gb,
          (__attribute__((address_space(3))) void*)(ldsB + i * 4096 + w * 1024),
          16, 0, 0);
    }
    __syncthreads();

    bf16x8 af[4][2], bfr[4][2];
#pragma unroll
    for (int m = 0; m < 4; ++m) {
      const int row = wm * 64 + m * 16 + lr;
#pragma unroll
      for (int kk = 0; kk < 2; ++kk) {
        const int slot = kk * 4 + lk;
        af[m][kk] =
            *(const bf16x8*)(ldsA + row * 128 + ((slot ^ (lr & 7)) << 4));
      }
    }
#pragma unroll
    for (int n = 0; n < 4; ++n) {
      const int row = wn * 64 + n * 16 + lr;
#pragma unroll
      for (int kk = 0; kk < 2; ++kk) {
        const int slot = kk * 4 + lk;
        bfr[n][kk] =
            *(const bf16x8*)(ldsB + row * 128 + ((slot ^ (lr & 7)) << 4));
      }
    }
#pragma unroll
    for (int m = 0; m < 4; ++m)
#pragma unroll
      for (int n = 0; n < 4; ++n) {
        acc[m][n] = __builtin_amdgcn_mfma_f32_16x16x32_bf16(
            af[m][0], bfr[n][0], acc[m][n], 0, 0, 0);
        acc[m][n] = __builtin_amdgcn_mfma_f32_16x16x32_bf16(
            af[m][1], bfr[n][1], acc[m][n], 0, 0, 0);
      }
  }

  const int or0 = bm + wm * 64 + lk * 4;
  const int oc0 = bn + wn * 64 + lr;
#pragma unroll
  for (int m = 0; m < 4; ++m)
#pragma unroll
    for (int n = 0; n < 4; ++n)
#pragma unroll
      for (int r = 0; r < 4; ++r) {
        float v = acc[m][n][r];
        const size_t off = (size_t)(or0 + m * 16 + r) * N + (oc0 + n * 16);
        if (SPLITK > 1) {
          ((bf16_t*)Cout)[bz * MN + off] = (bf16_t)v;
        } else {
          if (RELU) v = fmaxf(v, 0.f);
          if (ADDBF16)
            ((float*)Cout)[off] = v + (float)add[off];
          else
            ((bf16_t*)Cout)[off] = (bf16_t)v;
        }
      }
}

// reduce NPART bf16 partials -> relu -> bf16
template <int NPART>
__global__ __launch_bounds__(256) void reduceN_kernel(
    const bf16_t* __restrict__ p, bf16_t* __restrict__ out, int n8,
    size_t MN) {
  int i = blockIdx.x * 256 + threadIdx.x;
  if (i >= n8) return;
  float s[8] = {};
#pragma unroll
  for (int z = 0; z < NPART; ++z) {
    bf16x8 v = *(const bf16x8*)(p + z * MN + (size_t)i * 8);
#pragma unroll
    for (int j = 0; j < 8; ++j) s[j] += (float)v[j];
  }
  bf16x8 o;
#pragma unroll
  for (int j = 0; j < 8; ++j) o[j] = (bf16_t)fmaxf(s[j], 0.f);
  *(bf16x8*)(out + (size_t)i * 8) = o;
}

// ---------------------------------------------------------------------------
// prep_all (R12): ONE kernel fusing enc->bf16 cvt, all 4 weight transposes,
// and w1r reorder. Flattened grid, branch on block range (block-uniform).
//   [0,12800)       cvt enc (f32x4 -> bf16x4)
//   [12800,16896)   transT W_comp (K=4096,N=1024; nx=32)
//   [16896,17920)   transT W_ou1  (1024x1024; nx=32)
//   [17920,18944)   transT W_ofc  (1024x1024; nx=32)
//   [18944,23040)   transT W_dec  (K=1024,N=4096; nx=128)
//   [23040,23058)   w1r reorder (4590 elems)
// ---------------------------------------------------------------------------
__global__ __launch_bounds__(256) void prep_all(
    const float* __restrict__ enc, const float* __restrict__ Wcomp,
    const float* __restrict__ Wou1, const float* __restrict__ Wofc,
    const float* __restrict__ Wdec, const float* __restrict__ w1,
    bf16_t* __restrict__ encb, bf16_t* __restrict__ WcompT,
    bf16_t* __restrict__ Wou1T, bf16_t* __restrict__ WofcT,
    bf16_t* __restrict__ WdecT, float* __restrict__ w1r) {
  __shared__ float t[32][33];
  const int tid = threadIdx.x;
  int blk = blockIdx.x;

  if (blk < 12800) {  // cvt enc
    const int i = blk * 256 + tid;  // < 3,276,800 exactly
    float4 v = ((const float4*)enc)[i];
    bf16x4 o = {(bf16_t)v.x, (bf16_t)v.y, (bf16_t)v.z, (bf16_t)v.w};
    ((bf16x4*)encb)[i] = o;
    return;
  }
  blk -= 12800;

  const float* in;
  bf16_t* out;
  int K, N, nx;
  if (blk < 4096) {
    in = Wcomp; out = WcompT; K = 4096; N = 1024; nx = 32;
  } else if (blk < 4096 + 1024) {
    blk -= 4096;
    in = Wou1; out = Wou1T; K = 1024; N = 1024; nx = 32;
  } else if (blk < 4096 + 2048) {
    blk -= 4096 + 1024;
    in = Wofc; out = WofcT; K = 1024; N = 1024; nx = 32;
  } else if (blk < 4096 + 2048 + 4096) {
    blk -= 4096 + 2048;
    in = Wdec; out = WdecT; K = 1024; N = 4096; nx = 128;
  } else {  // w1r reorder
    blk -= 4096 + 2048 + 4096;
    const int idx = blk * 256 + tid;
    if (idx < NRCH * 90) {
      int ci = idx / 90, r = idx % 90, k9 = r / 10, co = r % 10;
      w1r[idx] = w1[((co * NRCH + ci) * 3 + k9 / 3) * 3 + (k9 % 3)];
    }
    return;
  }

  const int n0 = (blk % nx) * 32, k0 = (blk / nx) * 32;
  const int tx = tid & 31, ty = tid >> 5;  // 32 x 8
#pragma unroll
  for (int i = 0; i < 4; ++i)
    t[ty + i * 8][tx] = in[(size_t)(k0 + ty + i * 8) * N + n0 + tx];
  __syncthreads();
#pragma unroll
  for (int i = 0; i < 4; ++i)
    out[(size_t)(n0 + ty + i * 8) * K + k0 + tx] = (bf16_t)t[tx][ty + i * 8];
}

// ---------------------------------------------------------------------------
// femb1[p][k9][0..9] (stride 12) = sum_ci femb[p][ci] * w1r[ci][k9co]
// (coalesced w1r layout — R9 lesson: direct w1 read was 130 µs latency-bound)
// ---------------------------------------------------------------------------
__global__ __launch_bounds__(128) void femb1_kernel(
    const float* __restrict__ femb, const float* __restrict__ w1r,
    float* __restrict__ femb1) {
  __shared__ float row[NRCH];
  const int p = blockIdx.x;
  if (threadIdx.x < NRCH)
    row[threadIdx.x] = femb[(size_t)p * NRCH + threadIdx.x];
  __syncthreads();
  const int t = threadIdx.x;
  if (t >= 90) return;
  float acc = 0.f;
#pragma unroll
  for (int ci = 0; ci < NRCH; ++ci) acc += row[ci] * w1r[ci * 90 + t];
  femb1[((size_t)p * 9 + t / 10) * 12 + (t % 10)] = acc;
}

// ---------------------------------------------------------------------------
// conv_fused (R12): conv1-gather + conv2/conv3+tanh in ONE kernel.
// Block = (b, 16x16 output tile). Phase 1: build x1 halo tile 18x18x12 in
// LDS (conv1g logic; zero outside grid = conv2's zero-padding). Phase 2:
// 3x3 x 10ch contraction + tanh from LDS. Kills the 15.4 MB x1 round-trip.
// ---------------------------------------------------------------------------
__global__ __launch_bounds__(256) void conv_fused(
    const int* __restrict__ preds, const float* __restrict__ femb1,
    const float* __restrict__ w2, const float* __restrict__ w3,
    float* __restrict__ adj) {
  __shared__ float xt[18][18][12];
  __shared__ float w[90];
  const int tid = threadIdx.x;
  const int b = blockIdx.z;
  const int ti = blockIdx.y * 16, tj = blockIdx.x * 16;

  if (tid < 90) {  // fold conv3 into conv2 weights
    const int k9 = tid / 10, c2 = tid % 10;
    float a = 0.f;
#pragma unroll
    for (int c3 = 0; c3 < 5; ++c3)
      a += w3[c3] * w2[(c3 * 10 + c2) * 9 + k9];
    w[tid] = a;
  }

  const int* pr = preds + b * NOBJ;

  // phase 1: x1 on [ti-1, ti+17) x [tj-1, tj+17)
  for (int t = tid; t < 324; t += 256) {
    const int hi = t / 18, wj = t % 18;
    const int ii = ti - 1 + hi, jj = tj - 1 + wj;
    f32x4 a0 = {0.f, 0.f, 0.f, 0.f}, a1 = a0, a2 = a0;
    if (ii >= 0 && ii < NOBJ && jj >= 0 && jj < NOBJ) {
#pragma unroll
      for (int kh = 0; kh < 3; ++kh) {
        const int i2 = ii + kh - 1;
        if (i2 < 0 || i2 >= NOBJ) continue;
        const int li = pr[i2];
#pragma unroll
        for (int kw = 0; kw < 3; ++kw) {
          const int j2 = jj + kw - 1;
          if (j2 < 0 || j2 >= NOBJ) continue;
          const int p = li * NCC + pr[j2];
          const f32x4* f =
              (const f32x4*)(femb1 + ((size_t)p * 9 + kh * 3 + kw) * 12);
          a0 += f[0];
          a1 += f[1];
          a2 += f[2];
        }
      }
    }
    f32x4* o = (f32x4*)&xt[hi][wj][0];
    o[0] = a0;
    o[1] = a1;
    o[2] = a2;
  }
  __syncthreads();

  // phase 2: 16x16 outputs
  const int di = tid >> 4, dj = tid & 15;
  const int i = ti + di, j = tj + dj;
  if (i >= NOBJ || j >= NOBJ) return;
  float acc = 0.f;
#pragma unroll
  for (int kh = 0; kh < 3; ++kh)
#pragma unroll
    for (int kw = 0; kw < 3; ++kw) {
      const float* xr = &xt[di + kh][dj + kw][0];
      const float* wr = w + (kh * 3 + kw) * 10;
#pragma unroll
      for (int c = 0; c < 10; ++c) acc += wr[c] * xr[c];
    }
  adj[((size_t)b * NOBJ + i) * NOBJ + j] = tanhf(acc);
}

// ---------------------------------------------------------------------------
// einsum via MFMA: ofl_u[b] = adj[b] (100x100) @ u1[b] (100x1024)
// (R4-proven; swizzled LDS transpose-on-stage, K padded to 128, zeroed)
// ---------------------------------------------------------------------------
__global__ __launch_bounds__(256) void einsum_mfma_kernel(
    const float* __restrict__ adj, const bf16_t* __restrict__ u1,
    bf16_t* __restrict__ ofl) {
  __shared__ __align__(16) bf16_t As[128 * 128];
  __shared__ __align__(16) bf16_t Us[128 * 128];
  const int b = blockIdx.y;
  const int h0 = blockIdx.x * 128;
  const int tid = threadIdx.x, lane = tid & 63, w = tid >> 6;
  const int wm = w >> 1, wn = w & 1;
  const int lr = lane & 15, lk = lane >> 4;

  {
    f32x4 z = {0.f, 0.f, 0.f, 0.f};
#pragma unroll
    for (int i = 0; i < 8; ++i) ((f32x4*)As)[tid + i * 256] = z;
#pragma unroll
    for (int i = 0; i < 8; ++i) ((f32x4*)Us)[tid + i * 256] = z;
  }
  __syncthreads();

  const float* ab = adj + (size_t)b * 10000;
#pragma unroll
  for (int i = 0; i < 10; ++i) {
    int idx = tid + i * 256;
    if (idx < 2500) {
      int row = idx / 25, kc = idx % 25;
      f32x4 v = ((const f32x4*)ab)[idx];
      bf16x4 o = {(bf16_t)v[0], (bf16_t)v[1], (bf16_t)v[2], (bf16_t)v[3]};
      int slot = kc >> 1;
      *(bf16x4*)((char*)As + row * 256 + ((slot ^ (row & 7)) << 4) +
                 (kc & 1) * 8) = o;
    }
  }

  const bf16_t* ub = u1 + (size_t)b * 100 * HDIM + h0;
#pragma unroll
  for (int i = 0; i < 7; ++i) {
    int idx = tid + i * 256;
    if (idx < 1600) {
      int hc = idx / 100, m = idx % 100;
      bf16x8 v = *(const bf16x8*)(ub + (size_t)m * HDIM + hc * 8);
      int slot = m >> 3, mr = m & 7;
#pragma unroll
      for (int j = 0; j < 8; ++j) {
        int h = hc * 8 + j;
        *((bf16_t*)((char*)Us + h * 256 + ((slot ^ (h & 7)) << 4) + mr * 2)) =
            v[j];
      }
    }
  }
  __syncthreads();

  f32x4 acc[4][4];
#pragma unroll
  for (int m = 0; m < 4; ++m)
#pragma unroll
    for (int n = 0; n < 4; ++n) acc[m][n] = (f32x4){0.f, 0.f, 0.f, 0.f};

#pragma unroll
  for (int ks = 0; ks < 4; ++ks) {
    bf16x8 a[4], u[4];
#pragma unroll
    for (int m = 0; m < 4; ++m) {
      int row = wm * 64 + m * 16 + lr;
      int slot = ks * 4 + lk;
      a[m] = *(const bf16x8*)((char*)As + row * 256 + ((slot ^ (lr & 7)) << 4));
    }
#pragma unroll
    for (int n = 0; n < 4; ++n) {
      int row = wn * 64 + n * 16 + lr;
      int slot = ks * 4 + lk;
      u[n] = *(const bf16x8*)((char*)Us + row * 256 + ((slot ^ (lr & 7)) << 4));
    }
#pragma unroll
    for (int m = 0; m < 4; ++m)
#pragma unroll
      for (int n = 0; n < 4; ++n)
        acc[m][n] = __builtin_amdgcn_mfma_f32_16x16x32_bf16(a[m], u[n],
                                                            acc[m][n], 0, 0, 0);
  }

  const int or0 = wm * 64 + lk * 4;
  const int oc0 = h0 + wn * 64 + lr;
#pragma unroll
  for (int m = 0; m < 4; ++m)
#pragma unroll
    for (int n = 0; n < 4; ++n)
#pragma unroll
      for (int r = 0; r < 4; ++r) {
        int row = or0 + m * 16 + r;
        if (row < 100)
          ofl[((size_t)b * 100 + row) * HDIM + oc0 + n * 16] =
              (bf16_t)acc[m][n][r];
      }
}

// ---------------------------------------------------------------------------
extern "C" void kernel_launch(void* const* d_in, const int* in_sizes, int n_in,
                              void* d_out, int out_size, void* d_ws,
                              size_t ws_size, hipStream_t stream) {
  const float* enc = (const float*)d_in[0];
  const float* W_comp = (const float*)d_in[1];
  const float* W_ou1 = (const float*)d_in[2];
  const float* W_ofc = (const float*)d_in[3];
  const float* W_dec = (const float*)d_in[4];
  const float* conv1w = (const float*)d_in[5];
  const float* conv2w = (const float*)d_in[6];
  const float* conv3w = (const float*)d_in[7];
  const float* femb = (const float*)d_in[8];
  const int* preds = (const int*)d_in[9];
  float* out = (float*)d_out;
  char* wsb = (char*)d_ws;

  const size_t MN = (size_t)TDIM * HDIM;  // 3,276,800

  // workspace (bytes), peak ~80.0MB (<= 92.3MB proven).
  // Live-from-prep_all: encb (to G4), WcompT (to G1), Wou1T (to G2),
  // WofcT (to G3), WdecT (to G4), w1r (to femb1).
  // part4 [53.76M,79.97M) lives G1->reduce4 only; femb1/obj_u1/adj/u_m
  // overlay its dead region (all written after reduce4). ofl_u overlays
  // comp (dead after G2).
  bf16_t* encb   = (bf16_t*)(wsb + 0);           // 26,214,400
  bf16_t* WcompT = (bf16_t*)(wsb + 26214400);    //  8,388,608 (ends 34.60M)
  bf16_t* Wou1T  = (bf16_t*)(wsb + 34603008);    //  2,097,152 (ends 36.70M)
  bf16_t* WofcT  = (bf16_t*)(wsb + 36700160);    //  2,097,152 (ends 38.80M)
  bf16_t* WdecT  = (bf16_t*)(wsb + 38797312);    //  8,388,608 (ends 47.19M)
  float*  w1r    = (float*)(wsb + 47185920);     //     18,360 (ends 47.20M)
  bf16_t* comp   = (bf16_t*)(wsb + 47204352);    //  6,553,600 (ends 53.76M)
  bf16_t* part4  = (bf16_t*)(wsb + 53757952);    // 26,214,400 (ends 79.97M)
  float*  femb1  = (float*)(wsb + 53757952);     //  9,850,032 (after reduce4)
  bf16_t* obj_u1 = (bf16_t*)(wsb + 63608064);    //  6,553,600 (ends 70.16M)
  float*  adj    = (float*)(wsb + 70161664);     //  1,280,000 (ends 71.44M)
  bf16_t* u_m    = (bf16_t*)(wsb + 71441664);    //  6,553,600 (ends 78.00M)
  bf16_t* ofl_u  = (bf16_t*)(wsb + 47204352);    //  6,553,600 (over comp)

  const int n8 = (int)(MN / 8);  // 409,600 -> 1600 blocks for reduceN

  // 0. ALL conversions/reorders in one kernel (was 6 launches)
  prep_all<<<23058, 256, 0, stream>>>(enc, W_comp, W_ou1, W_ofc, W_dec,
                                      conv1w, encb, WcompT, Wou1T, WofcT,
                                      WdecT, w1r);

  // 1. comp = relu(enc @ W_comp)  M=3200 N=1024 K=4096
  //    split-K=4, MODE3 XCD-pair mapping (832 blocks) + reduce4
  gemm_bf16<false, false, 4, 3><<<dim3(832, 1, 1), 256, 0, stream>>>(
      encb, WcompT, nullptr, part4, HDIM, DDIM, MN);
  reduceN_kernel<4><<<n8 / 256, 256, 0, stream>>>(part4, comp, n8, MN);

  // 2. obj_u1 = relu(comp @ W_ou1) M=3200 N=1024 K=1024
  gemm_bf16<true, false, 1, 0>
      <<<dim3(HDIM / 128, TDIM / 128), 256, 0, stream>>>(
          comp, Wou1T, nullptr, obj_u1, HDIM, HDIM, MN);

  // 3. conv chain: femb1 then fused conv1+conv2+conv3+tanh
  femb1_kernel<<<NCC * NCC, 128, 0, stream>>>(femb, w1r, femb1);
  conv_fused<<<dim3(7, 7, BDIM), 256, 0, stream>>>(preds, femb1, conv2w,
                                                   conv3w, adj);

  // 4. einsum via MFMA -> ofl_u (bf16)
  einsum_mfma_kernel<<<dim3(HDIM / 128, BDIM), 256, 0, stream>>>(adj, obj_u1,
                                                                 ofl_u);

  // 5. u_m = relu(ofl_u @ W_ofc)  M=3200 N=1024 K=1024
  gemm_bf16<true, false, 1, 0>
      <<<dim3(HDIM / 128, TDIM / 128), 256, 0, stream>>>(
          ofl_u, WofcT, nullptr, u_m, HDIM, HDIM, MN);

  // 6. out = relu(u_m @ W_dec) + enc(bf16)  M=3200 N=4096 K=1024 (fp32 out)
  gemm_bf16<true, true, 1, 0>
      <<<dim3(DDIM / 128, TDIM / 128), 256, 0, stream>>>(
          u_m, WdecT, encb, out, DDIM, HDIM, MN);
}